// Round 4
// baseline (456.124 us; speedup 1.0000x reference)
//
#include <hip/hip_runtime.h>

// HGNN conv: out = degv ⊙ (H @ ((w*deg_e) ⊙ (H^T @ (degv ⊙ (x@W))))) + bias ; w = sigmoid(H^T (x V))
// N=8192, E=4096, F=512. R4: occupancy (split-K 8/4 + atomic partials), cvt_ubyte+perm expand,
// G1 full-DMA via pre-converted x bf16. ws footprint exactly 113,885,184 B (= R3-proven).

#define N_NODES 8192
#define N_EDGES 4096
#define FT 512

typedef short bf16x8 __attribute__((ext_vector_type(8)));
typedef float f32x4 __attribute__((ext_vector_type(4)));
typedef unsigned short u16;
typedef unsigned int u32;
typedef unsigned char u8;

__device__ __forceinline__ u16 f2b(float f) {
    union { float f; u32 u; } v; v.f = f;
    u32 r = v.u + 0x7FFFu + ((v.u >> 16) & 1u);   // RNE
    return (u16)(r >> 16);
}
// two 0/1 bytes (w bits 0-7, 8-15) -> packed 2x bf16 {lo, hi} via cvt_f32_ubyte + perm
__device__ __forceinline__ u32 pack2(u32 w) {
    union { float f; u32 u; } a, b;
    a.f = (float)(w & 0xFFu);          // v_cvt_f32_ubyte0 -> 0x3F800000 or 0
    b.f = (float)((w >> 8) & 0xFFu);   // v_cvt_f32_ubyte1
    return __builtin_amdgcn_perm(b.u, a.u, 0x07060302u);  // [b1.b3 b1.b2 a.b3 a.b2]
}

// ---------------- scalar-path kernels ----------------

__global__ __launch_bounds__(256) void zero_kernel(float* p, int n) {
    int i = blockIdx.x * 256 + threadIdx.x;
    if (i < n) p[i] = 0.f;
}
__global__ __launch_bounds__(256) void zero4_kernel(float4* p, int n4) {
    int i = blockIdx.x * 256 + threadIdx.x;
    if (i < n4) p[i] = (float4){0.f, 0.f, 0.f, 0.f};
}

// xv[n] = x[n,:] . V ; also xb = bf16(x) row
__global__ __launch_bounds__(256) void xv_xb_kernel(const float* __restrict__ x,
                                                    const float* __restrict__ V,
                                                    float* __restrict__ xv,
                                                    u16* __restrict__ xb) {
    int row = blockIdx.x * 4 + (threadIdx.x >> 6);
    int lane = threadIdx.x & 63;
    const float* xr = x + (size_t)row * FT + lane * 8;
    const float* vr = V + lane * 8;
    float4 a0 = *(const float4*)xr, a1 = *(const float4*)(xr + 4);
    float4 b0 = *(const float4*)vr, b1 = *(const float4*)(vr + 4);
    float acc = a0.x * b0.x + a0.y * b0.y + a0.z * b0.z + a0.w * b0.w +
                a1.x * b1.x + a1.y * b1.y + a1.z * b1.z + a1.w * b1.w;
    u16 tmp[8] = {f2b(a0.x), f2b(a0.y), f2b(a0.z), f2b(a0.w),
                  f2b(a1.x), f2b(a1.y), f2b(a1.z), f2b(a1.w)};
    *(uint4*)(xb + (size_t)row * FT + lane * 8) = *(uint4*)tmp;
#pragma unroll
    for (int off = 32; off; off >>= 1) acc += __shfl_down(acc, off);
    if (lane == 0) xv[row] = acc;
}

// Hu8 = (u8)H ; zsum[e] += sum_n H[n,e]*xv[n] ; desum[e] += sum_n H[n,e]
__global__ __launch_bounds__(256) void cvt_colsum_kernel(const float* __restrict__ H,
                                                         const float* __restrict__ xv,
                                                         u8* __restrict__ Hu8,
                                                         float* __restrict__ zsum,
                                                         float* __restrict__ desum) {
    int e0 = (blockIdx.x * 256 + threadIdx.x) * 4;
    int n0 = blockIdx.y * 32;
    float z0 = 0.f, z1 = 0.f, z2 = 0.f, z3 = 0.f;
    float d0 = 0.f, d1 = 0.f, d2 = 0.f, d3 = 0.f;
#pragma unroll 4
    for (int i = 0; i < 32; i++) {
        int n = n0 + i;
        float4 h = *(const float4*)(H + (size_t)n * N_EDGES + e0);
        float xvn = xv[n];
        z0 += h.x * xvn; z1 += h.y * xvn; z2 += h.z * xvn; z3 += h.w * xvn;
        d0 += h.x; d1 += h.y; d2 += h.z; d3 += h.w;
        u32 p = (u32)h.x | ((u32)h.y << 8) | ((u32)h.z << 16) | ((u32)h.w << 24);
        *(u32*)(Hu8 + (size_t)n * N_EDGES + e0) = p;
    }
    atomicAdd(zsum + e0 + 0, z0); atomicAdd(zsum + e0 + 1, z1);
    atomicAdd(zsum + e0 + 2, z2); atomicAdd(zsum + e0 + 3, z3);
    atomicAdd(desum + e0 + 0, d0); atomicAdd(desum + e0 + 1, d1);
    atomicAdd(desum + e0 + 2, d2); atomicAdd(desum + e0 + 3, d3);
}

__global__ __launch_bounds__(256) void sigmoid_kernel(const float* __restrict__ zsum,
                                                      const float* __restrict__ desum,
                                                      float* __restrict__ w_out,
                                                      float* __restrict__ wde) {
    int e = blockIdx.x * 256 + threadIdx.x;
    float z = zsum[e];
    float wv = 1.f / (1.f + expf(-z));
    w_out[e] = wv;
    wde[e] = wv * desum[e];
}

// degv[n] = Hu8[n,:] . w
__global__ __launch_bounds__(256) void degv_kernel(const u8* __restrict__ Hu8,
                                                   const float* __restrict__ w,
                                                   float* __restrict__ degv) {
    int row = blockIdx.x * 4 + (threadIdx.x >> 6);
    int lane = threadIdx.x & 63;
    const u32* hr = (const u32*)(Hu8 + (size_t)row * N_EDGES);
    const float4* wr = (const float4*)w;
    float acc = 0.f;
#pragma unroll
    for (int i = 0; i < 16; i++) {
        int idx = i * 64 + lane;
        u32 h4 = hr[idx];
        float4 ww = wr[idx];
        if (h4 & 0x000000FFu) acc += ww.x;
        if (h4 & 0x0000FF00u) acc += ww.y;
        if (h4 & 0x00FF0000u) acc += ww.z;
        if (h4 & 0xFF000000u) acc += ww.w;
    }
#pragma unroll
    for (int off = 32; off; off >>= 1) acc += __shfl_down(acc, off);
    if (lane == 0) degv[row] = acc;
}

// W (FT,FT) fp32 -> WT (FT,FT) bf16 transposed
__global__ void wt_kernel(const float* __restrict__ src, u16* __restrict__ dst) {
    __shared__ float tile[32][33];
    int tx = threadIdx.x, ty = threadIdx.y;
    int c = blockIdx.x * 32 + tx;
    int r0 = blockIdx.y * 32;
#pragma unroll
    for (int i = 0; i < 4; i++)
        tile[ty + i * 8][tx] = src[(size_t)(r0 + ty + i * 8) * FT + c];
    __syncthreads();
#pragma unroll
    for (int i = 0; i < 4; i++)
        dst[(size_t)(blockIdx.x * 32 + ty + i * 8) * FT + r0 + tx] = f2b(tile[tx][ty + i * 8]);
}

// Hu8 (N,E) -> HTu8 (E,N) : 64x64 u8 tiles
__global__ __launch_bounds__(256) void transH_kernel(const u8* __restrict__ Hu8,
                                                     u8* __restrict__ HTu8) {
    __shared__ u32 tile[64][17];
    const int t = threadIdx.x;
    const int e0 = blockIdx.x * 64, n0 = blockIdx.y * 64;
    {
        int nl = t >> 2, seg = t & 3;
        uint4 v = *(const uint4*)(Hu8 + (size_t)(n0 + nl) * N_EDGES + e0 + seg * 16);
        tile[nl][seg * 4 + 0] = v.x; tile[nl][seg * 4 + 1] = v.y;
        tile[nl][seg * 4 + 2] = v.z; tile[nl][seg * 4 + 3] = v.w;
    }
    __syncthreads();
    int ew = t >> 4, ng = t & 15;
    u32 a0 = tile[ng * 4 + 0][ew], a1 = tile[ng * 4 + 1][ew];
    u32 a2 = tile[ng * 4 + 2][ew], a3 = tile[ng * 4 + 3][ew];
#pragma unroll
    for (int i = 0; i < 4; i++) {
        u32 o = ((a0 >> (8 * i)) & 0xFFu) | (((a1 >> (8 * i)) & 0xFFu) << 8) |
                (((a2 >> (8 * i)) & 0xFFu) << 16) | (((a3 >> (8 * i)) & 0xFFu) << 24);
        *(u32*)(HTu8 + (size_t)(e0 + ew * 4 + i) * N_NODES + n0 + ng * 4) = o;
    }
}

// t2T[f,e] = f2b(wde[e] * Pt2[e][f])
__global__ void t2t_kernel(const float* __restrict__ P, const float* __restrict__ wde,
                           u16* __restrict__ t2T) {
    __shared__ float tile[32][33];
    int tx = threadIdx.x, ty = threadIdx.y;
    int f0 = blockIdx.x * 32, e0 = blockIdx.y * 32;
#pragma unroll
    for (int i = 0; i < 4; i++) {
        int e = e0 + ty + i * 8;
        tile[ty + i * 8][tx] = wde[e] * P[(size_t)e * FT + f0 + tx];
    }
    __syncthreads();
#pragma unroll
    for (int i = 0; i < 4; i++)
        t2T[(size_t)(f0 + ty + i * 8) * N_EDGES + e0 + tx] = f2b(tile[tx][ty + i * 8]);
}

// out[n,f] = degv[n]*P[n,f] + bias[f]
__global__ __launch_bounds__(256) void final_kernel(const float* __restrict__ P,
                                                    const float* __restrict__ degv,
                                                    const float* __restrict__ bias,
                                                    float* __restrict__ out) {
    int i4 = blockIdx.x * 256 + threadIdx.x;
    int base = i4 * 4;
    int n = base >> 9, f = base & 511;
    float4 a = *(const float4*)(P + base);
    float4 bi = *(const float4*)(bias + f);
    float dv = degv[n];
    float4 o;
    o.x = dv * a.x + bi.x; o.y = dv * a.y + bi.y;
    o.z = dv * a.z + bi.z; o.w = dv * a.w + bi.w;
    *(float4*)(out + base) = o;
}

// ---------------- MFMA GEMM ----------------
// Tile TBM x 128, TBM = MT*32. 4 waves (2x2): wave covers (MT*16) x 64 via MTx4 16x16x32 MFMAs.
// LDS unpadded [row][32] bf16 (global_load_lds layout).
// ASRC: 0 = bf16 row-major via global_load_lds (MT*1024/2048 elts), 1 = u8 row-major (cvt+perm expand; MT=4)
// EPI:  0 = atomicAdd fp32 C[m*ldc+n], 1 = bf16 store C[m*ldc+n] scaled by degv[n]

#define TBK 32

template <int MT, int ASRC, int EPI>
__global__ __launch_bounds__(256)
void gemm4(const void* __restrict__ Ap, const void* __restrict__ Bp,
           void* __restrict__ Cp, const float* __restrict__ degv,
           int KC, int lda, int ldb, int ldc) {
    __shared__ __align__(16) u16 Alds[MT * 32 * TBK];
    __shared__ __align__(16) u16 Blds[128 * TBK];
    const int t = threadIdx.x;
    const int m0 = blockIdx.x * (MT * 32), n0 = blockIdx.y * 128;
    const int kbase = blockIdx.z * KC;
    const int wave = t >> 6, lane = t & 63, quad = lane >> 4, lo = lane & 15;
    const int wm = (wave >> 1) * (MT * 16), wn = (wave & 1) * 64;

    f32x4 acc[MT][4];
#pragma unroll
    for (int a = 0; a < MT; a++)
#pragma unroll
        for (int b = 0; b < 4; b++) acc[a][b] = (f32x4){0.f, 0.f, 0.f, 0.f};

    for (int kk = 0; kk < KC; kk += TBK) {
        const int k0 = kbase + kk;
        __syncthreads();
        // ---- stage A ----
        if (ASRC == 0) {
            const u16* A = (const u16*)Ap;
#pragma unroll
            for (int i = 0; i < MT / 2; i++) {
                int c = t + i * 256;
                const u16* g = A + (size_t)(m0 + (c >> 2)) * lda + k0 + (c & 3) * 8;
                __builtin_amdgcn_global_load_lds((const u32*)g, (u32*)(Alds + c * 8), 16, 0, 0);
            }
        } else {
            const u8* A = (const u8*)Ap;
            const int r = t >> 1, h = (t & 1) * 16;
            uint4 v = *(const uint4*)(A + (size_t)(m0 + r) * lda + k0 + h);
            u32 o[8];
            o[0] = pack2(v.x); o[1] = pack2(v.x >> 16);
            o[2] = pack2(v.y); o[3] = pack2(v.y >> 16);
            o[4] = pack2(v.z); o[5] = pack2(v.z >> 16);
            o[6] = pack2(v.w); o[7] = pack2(v.w >> 16);
            *(uint4*)&Alds[r * TBK + h]     = *(uint4*)&o[0];
            *(uint4*)&Alds[r * TBK + h + 8] = *(uint4*)&o[4];
        }
        // ---- stage B (bf16 DMA) ----
        {
            const u16* B = (const u16*)Bp;
#pragma unroll
            for (int i = 0; i < 2; i++) {
                int c = t + i * 256;
                const u16* g = B + (size_t)(n0 + (c >> 2)) * ldb + k0 + (c & 3) * 8;
                __builtin_amdgcn_global_load_lds((const u32*)g, (u32*)(Blds + c * 8), 16, 0, 0);
            }
        }
        __syncthreads();

        bf16x8 af[MT], bfr[4];
#pragma unroll
        for (int mt = 0; mt < MT; mt++)
            af[mt] = *(const bf16x8*)&Alds[(wm + mt * 16 + lo) * TBK + quad * 8];
#pragma unroll
        for (int nt = 0; nt < 4; nt++)
            bfr[nt] = *(const bf16x8*)&Blds[(wn + nt * 16 + lo) * TBK + quad * 8];
#pragma unroll
        for (int mt = 0; mt < MT; mt++)
#pragma unroll
            for (int nt = 0; nt < 4; nt++)
                acc[mt][nt] = __builtin_amdgcn_mfma_f32_16x16x32_bf16(af[mt], bfr[nt], acc[mt][nt], 0, 0, 0);
    }

    // epilogue: D[row=quad*4+i][col=lo] per 16x16 tile
    if (EPI == 0) {
        float* C = (float*)Cp;
#pragma unroll
        for (int mt = 0; mt < MT; mt++) {
            int rb = m0 + wm + mt * 16 + quad * 4;
#pragma unroll
            for (int i = 0; i < 4; i++)
#pragma unroll
                for (int nt = 0; nt < 4; nt++)
                    atomicAdd(&C[(size_t)(rb + i) * ldc + n0 + wn + nt * 16 + lo], acc[mt][nt][i]);
        }
    } else {
        u16* C = (u16*)Cp;
        float dv[4];
#pragma unroll
        for (int nt = 0; nt < 4; nt++) dv[nt] = degv[n0 + wn + nt * 16 + lo];
#pragma unroll
        for (int mt = 0; mt < MT; mt++) {
            int rb = m0 + wm + mt * 16 + quad * 4;
#pragma unroll
            for (int i = 0; i < 4; i++)
#pragma unroll
                for (int nt = 0; nt < 4; nt++)
                    C[(size_t)(rb + i) * ldc + n0 + wn + nt * 16 + lo] =
                        f2b(acc[mt][nt][i] * dv[nt]);
        }
    }
}

// ---------------- launch ----------------

extern "C" void kernel_launch(void* const* d_in, const int* in_sizes, int n_in,
                              void* d_out, int out_size, void* d_ws, size_t ws_size,
                              hipStream_t stream) {
    const float* x    = (const float*)d_in[0];
    const float* H    = (const float*)d_in[1];
    const float* W    = (const float*)d_in[2];
    const float* V    = (const float*)d_in[3];
    const float* bias = (const float*)d_in[4];
    float* out  = (float*)d_out;                       // (N, FT)
    float* wout = out + (size_t)N_NODES * FT;          // (E,)
    (void)in_sizes; (void)n_in; (void)out_size; (void)ws_size;

    char* wsb = (char*)d_ws;
    float* wsf   = (float*)d_ws;
    float* xv    = wsf;               // 8192 f
    float* zsum  = wsf + 8192;        // 4096 f
    float* desum = wsf + 12288;       // 4096 f
    float* wde   = wsf + 16384;       // 4096 f
    float* degv  = wsf + 20480;       // 8192 f -> 114,688 B
    u8*    Hu8   = (u8*)(wsb + 114688);                  // 32 MB  -> 33,669,120
    u8*    HTu8  = (u8*)(wsb + 33669120);                // 32 MB  -> 67,223,552
    u16*   WT    = (u16*)(wsb + 67223552);               // 0.5 MB -> 67,747,840
    u16*   doutT = (u16*)(wsb + 67747840);               // 8 MB   -> 76,136,448
    u16*   t2T   = (u16*)(wsb + 76136448);               // 4 MB   -> 80,330,752
    u16*   xb    = (u16*)(wsb + 80330752);               // 8 MB   -> 88,719,360
    float* Pt2   = (float*)(wsb + 88719360);             // 8 MB   -> 97,107,968
    float* Pout  = (float*)(wsb + 97107968);             // 16 MB  -> 113,885,184 (== R3-proven)

    // zeros: zsum+desum (contig 8192 f), Pt2+Pout (contig 6M f)
    zero_kernel<<<32, 256, 0, stream>>>(zsum, 8192);
    zero4_kernel<<<6144, 256, 0, stream>>>((float4*)Pt2, 1572864);

    // scalar path
    xv_xb_kernel<<<N_NODES / 4, 256, 0, stream>>>(x, V, xv, xb);
    cvt_colsum_kernel<<<dim3(4, 256), 256, 0, stream>>>(H, xv, Hu8, zsum, desum);
    sigmoid_kernel<<<N_EDGES / 256, 256, 0, stream>>>(zsum, desum, wout, wde);
    degv_kernel<<<N_NODES / 4, 256, 0, stream>>>(Hu8, wout, degv);
    wt_kernel<<<dim3(16, 16), dim3(32, 8), 0, stream>>>(W, WT);
    transH_kernel<<<dim3(N_EDGES / 64, N_NODES / 64), 256, 0, stream>>>(Hu8, HTu8);

    // G1: doutT[f,n] = degv[n] * sum_fi WT[f,fi]*xb[n,fi]   (M=512, N=8192, K=512) 64x128 tile
    gemm4<2, 0, 1><<<dim3(FT / 64, N_NODES / 128), 256, 0, stream>>>(
        WT, xb, doutT, degv, FT, FT, FT, N_NODES);

    // G2: Pt2[e,f] += sum_n HTu8[e,n]*doutT[f,n]   (M=4096, N=512, K=8192, S=8)
    gemm4<4, 1, 0><<<dim3(N_EDGES / 128, FT / 128, 8), 256, 0, stream>>>(
        HTu8, doutT, Pt2, nullptr, N_NODES / 8, N_NODES, N_NODES, FT);

    // t2T[f,e] = wde[e] * Pt2[e,f]
    t2t_kernel<<<dim3(FT / 32, N_EDGES / 32), dim3(32, 8), 0, stream>>>(Pt2, wde, t2T);

    // G3: Pout[n,f] += sum_e Hu8[n,e]*t2T[f,e]   (M=8192, N=512, K=4096, S=4)
    gemm4<4, 1, 0><<<dim3(N_NODES / 128, FT / 128, 4), 256, 0, stream>>>(
        Hu8, t2T, Pout, nullptr, N_EDGES / 4, N_EDGES, N_EDGES, FT);

    // out = degv ⊙ Pout + bias
    final_kernel<<<(N_NODES * FT / 4) / 256, 256, 0, stream>>>(Pout, degv, bias, out);
}

// Round 6
// 386.784 us; speedup vs baseline: 1.1793x; 1.1793x over previous
//
#include <hip/hip_runtime.h>

// HGNN conv: out = degv ⊙ (H @ ((w*deg_e) ⊙ (H^T @ (degv ⊙ (x@W))))) + bias ; w = sigmoid(H^T (x V))
// N=8192, E=4096, F=512. R6 = R5 with the BSRC=0 staging index bug fixed
// (row=c>>2, chunk=(c&3)*8, dst=Blds+c*8 — the R3/R4-proven pattern).
// 128x256 GEMM tiles, no atomics (bf16 split partials + fused reduce). ws = 113,885,184 B.

#define N_NODES 8192
#define N_EDGES 4096
#define FT 512

typedef short bf16x8 __attribute__((ext_vector_type(8)));
typedef float f32x4 __attribute__((ext_vector_type(4)));
typedef unsigned short u16;
typedef unsigned int u32;
typedef unsigned char u8;

__device__ __forceinline__ u16 f2b(float f) {
    union { float f; u32 u; } v; v.f = f;
    u32 r = v.u + 0x7FFFu + ((v.u >> 16) & 1u);   // RNE
    return (u16)(r >> 16);
}
__device__ __forceinline__ float b2f(u16 h) {
    union { u32 u; float f; } v; v.u = ((u32)h) << 16; return v.f;
}
// two 0/1 bytes (w bits 0-7, 8-15) -> packed 2x bf16 {lo, hi} via cvt_f32_ubyte + perm
__device__ __forceinline__ u32 pack2(u32 w) {
    union { float f; u32 u; } a, b;
    a.f = (float)(w & 0xFFu);          // v_cvt_f32_ubyte0 -> 0x3F800000 or 0
    b.f = (float)((w >> 8) & 0xFFu);   // v_cvt_f32_ubyte1
    return __builtin_amdgcn_perm(b.u, a.u, 0x07060302u);
}

// ---------------- scalar-path kernels ----------------

__global__ __launch_bounds__(256) void zero_kernel(float* p, int n) {
    int i = blockIdx.x * 256 + threadIdx.x;
    if (i < n) p[i] = 0.f;
}

// xv[n] = x[n,:] . V
__global__ __launch_bounds__(256) void xv_kernel(const float* __restrict__ x,
                                                 const float* __restrict__ V,
                                                 float* __restrict__ xv) {
    int row = blockIdx.x * 4 + (threadIdx.x >> 6);
    int lane = threadIdx.x & 63;
    const float* xr = x + (size_t)row * FT + lane * 8;
    const float* vr = V + lane * 8;
    float4 a0 = *(const float4*)xr, a1 = *(const float4*)(xr + 4);
    float4 b0 = *(const float4*)vr, b1 = *(const float4*)(vr + 4);
    float acc = a0.x * b0.x + a0.y * b0.y + a0.z * b0.z + a0.w * b0.w +
                a1.x * b1.x + a1.y * b1.y + a1.z * b1.z + a1.w * b1.w;
#pragma unroll
    for (int off = 32; off; off >>= 1) acc += __shfl_down(acc, off);
    if (lane == 0) xv[row] = acc;
}

// Hu8 = (u8)H ; zsum[e] += sum_n H[n,e]*xv[n] ; desum[e] += sum_n H[n,e]
__global__ __launch_bounds__(256) void cvt_colsum_kernel(const float* __restrict__ H,
                                                         const float* __restrict__ xv,
                                                         u8* __restrict__ Hu8,
                                                         float* __restrict__ zsum,
                                                         float* __restrict__ desum) {
    int e0 = (blockIdx.x * 256 + threadIdx.x) * 4;
    int n0 = blockIdx.y * 32;
    float z0 = 0.f, z1 = 0.f, z2 = 0.f, z3 = 0.f;
    float d0 = 0.f, d1 = 0.f, d2 = 0.f, d3 = 0.f;
#pragma unroll 4
    for (int i = 0; i < 32; i++) {
        int n = n0 + i;
        float4 h = *(const float4*)(H + (size_t)n * N_EDGES + e0);
        float xvn = xv[n];
        z0 += h.x * xvn; z1 += h.y * xvn; z2 += h.z * xvn; z3 += h.w * xvn;
        d0 += h.x; d1 += h.y; d2 += h.z; d3 += h.w;
        u32 p = (u32)h.x | ((u32)h.y << 8) | ((u32)h.z << 16) | ((u32)h.w << 24);
        *(u32*)(Hu8 + (size_t)n * N_EDGES + e0) = p;
    }
    atomicAdd(zsum + e0 + 0, z0); atomicAdd(zsum + e0 + 1, z1);
    atomicAdd(zsum + e0 + 2, z2); atomicAdd(zsum + e0 + 3, z3);
    atomicAdd(desum + e0 + 0, d0); atomicAdd(desum + e0 + 1, d1);
    atomicAdd(desum + e0 + 2, d2); atomicAdd(desum + e0 + 3, d3);
}

__global__ __launch_bounds__(256) void sigmoid_kernel(const float* __restrict__ zsum,
                                                      const float* __restrict__ desum,
                                                      float* __restrict__ w_out,
                                                      float* __restrict__ wde) {
    int e = blockIdx.x * 256 + threadIdx.x;
    float z = zsum[e];
    float wv = 1.f / (1.f + expf(-z));
    w_out[e] = wv;
    wde[e] = wv * desum[e];
}

// degv[n] = Hu8[n,:] . w
__global__ __launch_bounds__(256) void degv_kernel(const u8* __restrict__ Hu8,
                                                   const float* __restrict__ w,
                                                   float* __restrict__ degv) {
    int row = blockIdx.x * 4 + (threadIdx.x >> 6);
    int lane = threadIdx.x & 63;
    const u32* hr = (const u32*)(Hu8 + (size_t)row * N_EDGES);
    const float4* wr = (const float4*)w;
    float acc = 0.f;
#pragma unroll
    for (int i = 0; i < 16; i++) {
        int idx = i * 64 + lane;
        u32 h4 = hr[idx];
        float4 ww = wr[idx];
        if (h4 & 0x000000FFu) acc += ww.x;
        if (h4 & 0x0000FF00u) acc += ww.y;
        if (h4 & 0x00FF0000u) acc += ww.z;
        if (h4 & 0xFF000000u) acc += ww.w;
    }
#pragma unroll
    for (int off = 32; off; off >>= 1) acc += __shfl_down(acc, off);
    if (lane == 0) degv[row] = acc;
}

// W (FT,FT) fp32 -> WT (FT,FT) bf16 transposed
__global__ void wt_kernel(const float* __restrict__ src, u16* __restrict__ dst) {
    __shared__ float tile[32][33];
    int tx = threadIdx.x, ty = threadIdx.y;
    int c = blockIdx.x * 32 + tx;
    int r0 = blockIdx.y * 32;
#pragma unroll
    for (int i = 0; i < 4; i++)
        tile[ty + i * 8][tx] = src[(size_t)(r0 + ty + i * 8) * FT + c];
    __syncthreads();
#pragma unroll
    for (int i = 0; i < 4; i++)
        dst[(size_t)(blockIdx.x * 32 + ty + i * 8) * FT + r0 + tx] = f2b(tile[tx][ty + i * 8]);
}

// Hu8 (N,E) -> HTu8 (E,N) : 64x64 u8 tiles
__global__ __launch_bounds__(256) void transH_kernel(const u8* __restrict__ Hu8,
                                                     u8* __restrict__ HTu8) {
    __shared__ u32 tile[64][17];
    const int t = threadIdx.x;
    const int e0 = blockIdx.x * 64, n0 = blockIdx.y * 64;
    {
        int nl = t >> 2, seg = t & 3;
        uint4 v = *(const uint4*)(Hu8 + (size_t)(n0 + nl) * N_EDGES + e0 + seg * 16);
        tile[nl][seg * 4 + 0] = v.x; tile[nl][seg * 4 + 1] = v.y;
        tile[nl][seg * 4 + 2] = v.z; tile[nl][seg * 4 + 3] = v.w;
    }
    __syncthreads();
    int ew = t >> 4, ng = t & 15;
    u32 a0 = tile[ng * 4 + 0][ew], a1 = tile[ng * 4 + 1][ew];
    u32 a2 = tile[ng * 4 + 2][ew], a3 = tile[ng * 4 + 3][ew];
#pragma unroll
    for (int i = 0; i < 4; i++) {
        u32 o = ((a0 >> (8 * i)) & 0xFFu) | (((a1 >> (8 * i)) & 0xFFu) << 8) |
                (((a2 >> (8 * i)) & 0xFFu) << 16) | (((a3 >> (8 * i)) & 0xFFu) << 24);
        *(u32*)(HTu8 + (size_t)(e0 + ew * 4 + i) * N_NODES + n0 + ng * 4) = o;
    }
}

// t2T[f,e] = f2b(wde[e] * sum_{s<8} P[s][e][f])   P: u16 slices of (E,512)
__global__ void t2t_kernel(const u16* __restrict__ P, const float* __restrict__ wde,
                           u16* __restrict__ t2T) {
    __shared__ float tile[32][33];
    int tx = threadIdx.x, ty = threadIdx.y;
    int f0 = blockIdx.x * 32, e0 = blockIdx.y * 32;
#pragma unroll
    for (int i = 0; i < 4; i++) {
        int e = e0 + ty + i * 8;
        size_t idx = (size_t)e * 512 + f0 + tx;
        float s = 0.f;
#pragma unroll
        for (int sl = 0; sl < 8; sl++)
            s += b2f(P[idx + (size_t)sl * N_EDGES * 512]);
        tile[ty + i * 8][tx] = wde[e] * s;
    }
    __syncthreads();
#pragma unroll
    for (int i = 0; i < 4; i++)
        t2T[(size_t)(f0 + ty + i * 8) * N_EDGES + e0 + tx] = f2b(tile[tx][ty + i * 8]);
}

// out[n,f] = degv[n]*sum_{s<4} P[s][n][f] + bias[f]   P: u16 slices of (N,512)
__global__ __launch_bounds__(256) void final_kernel(const u16* __restrict__ P,
                                                    const float* __restrict__ degv,
                                                    const float* __restrict__ bias,
                                                    float* __restrict__ out) {
    int i8 = blockIdx.x * 256 + threadIdx.x;
    int base = i8 * 8;
    int n = base >> 9, f = base & 511;
    float s[8] = {0.f, 0.f, 0.f, 0.f, 0.f, 0.f, 0.f, 0.f};
#pragma unroll
    for (int sl = 0; sl < 4; sl++) {
        uint4 v = *(const uint4*)(P + (size_t)sl * N_NODES * 512 + base);
        u32 ws[4] = {v.x, v.y, v.z, v.w};
#pragma unroll
        for (int j = 0; j < 4; j++) {
            s[2 * j]     += b2f((u16)(ws[j] & 0xFFFFu));
            s[2 * j + 1] += b2f((u16)(ws[j] >> 16));
        }
    }
    float dv = degv[n];
    float4 o0, o1;
    o0.x = dv * s[0] + bias[f + 0]; o0.y = dv * s[1] + bias[f + 1];
    o0.z = dv * s[2] + bias[f + 2]; o0.w = dv * s[3] + bias[f + 3];
    o1.x = dv * s[4] + bias[f + 4]; o1.y = dv * s[5] + bias[f + 5];
    o1.z = dv * s[6] + bias[f + 6]; o1.w = dv * s[7] + bias[f + 7];
    *(float4*)(out + base) = o0;
    *(float4*)(out + base + 4) = o1;
}

// ---------------- MFMA GEMM ----------------
// Tile (MT*32) x (NT*32), 4 waves (2x2): wave = (MT*16) x (NT*16), MT x NT 16x16x32 MFMAs.
// LDS unpadded [row][32] bf16 (global_load_lds layout).
// ASRC: 0 = bf16 row-major DMA (MT even), 1 = u8 row-major expand (MT=4 only)
// BSRC: 0 = bf16 Bt row-major DMA, 2 = fp32 Bt row-major convert
// EPI:  0 = bf16 partial store at Cp + z*Msz*512, ldc=512
//       1 = bf16 store C[m*ldc+n] scaled by degv[n]

#define TBK 32

template <int MT, int NT, int ASRC, int BSRC, int EPI>
__global__ __launch_bounds__(256, 2)
void gemm5(const void* __restrict__ Ap, const void* __restrict__ Bp,
           void* __restrict__ Cp, const float* __restrict__ degv,
           int KC, int lda, int ldb, int ldc, int Msz) {
    __shared__ __align__(16) u16 Alds[MT * 32 * TBK];
    __shared__ __align__(16) u16 Blds[NT * 32 * TBK];
    const int t = threadIdx.x;
    const int m0 = blockIdx.x * (MT * 32), n0 = blockIdx.y * (NT * 32);
    const int kbase = blockIdx.z * KC;
    const int wave = t >> 6, lane = t & 63, quad = lane >> 4, lo = lane & 15;
    const int wm = (wave >> 1) * (MT * 16), wn = (wave & 1) * (NT * 16);

    f32x4 acc[MT][NT];
#pragma unroll
    for (int a = 0; a < MT; a++)
#pragma unroll
        for (int b = 0; b < NT; b++) acc[a][b] = (f32x4){0.f, 0.f, 0.f, 0.f};

    for (int kk = 0; kk < KC; kk += TBK) {
        const int k0 = kbase + kk;
        __syncthreads();
        // ---- stage A ----
        if (ASRC == 0) {
            const u16* A = (const u16*)Ap;
#pragma unroll
            for (int i = 0; i < MT / 2; i++) {
                int c = t + i * 256;                               // chunk id
                const u16* g = A + (size_t)(m0 + (c >> 2)) * lda + k0 + (c & 3) * 8;
                __builtin_amdgcn_global_load_lds((const u32*)g, (u32*)(Alds + c * 8), 16, 0, 0);
            }
        } else {
            const u8* A = (const u8*)Ap;                 // MT == 4
            const int r = t >> 1, h = (t & 1) * 16;
            uint4 v = *(const uint4*)(A + (size_t)(m0 + r) * lda + k0 + h);
            u32 o[8];
            o[0] = pack2(v.x); o[1] = pack2(v.x >> 16);
            o[2] = pack2(v.y); o[3] = pack2(v.y >> 16);
            o[4] = pack2(v.z); o[5] = pack2(v.z >> 16);
            o[6] = pack2(v.w); o[7] = pack2(v.w >> 16);
            *(uint4*)&Alds[r * TBK + h]     = *(uint4*)&o[0];
            *(uint4*)&Alds[r * TBK + h + 8] = *(uint4*)&o[4];
        }
        // ---- stage B ----
        if (BSRC == 0) {
            const u16* B = (const u16*)Bp;
#pragma unroll
            for (int i = 0; i < NT / 2; i++) {
                int c = t + i * 256;                               // chunk id (FIXED: row=c>>2, chunk=c&3)
                const u16* g = B + (size_t)(n0 + (c >> 2)) * ldb + k0 + (c & 3) * 8;
                __builtin_amdgcn_global_load_lds((const u32*)g, (u32*)(Blds + c * 8), 16, 0, 0);
            }
        } else {
            const float* B = (const float*)Bp;           // NT == 4
            const int n = t >> 1, c0 = (t & 1) * 16;
            const float4* src = (const float4*)(B + (size_t)(n0 + n) * ldb + k0 + c0);
            float4 f[4];
#pragma unroll
            for (int i = 0; i < 4; i++) f[i] = src[i];
            u16 tmp[16];
#pragma unroll
            for (int i = 0; i < 4; i++) {
                tmp[4 * i + 0] = f2b(f[i].x); tmp[4 * i + 1] = f2b(f[i].y);
                tmp[4 * i + 2] = f2b(f[i].z); tmp[4 * i + 3] = f2b(f[i].w);
            }
            *(uint4*)&Blds[n * TBK + c0]     = *(uint4*)&tmp[0];
            *(uint4*)&Blds[n * TBK + c0 + 8] = *(uint4*)&tmp[8];
        }
        __syncthreads();

        bf16x8 af[MT], bfr[NT];
#pragma unroll
        for (int mt = 0; mt < MT; mt++)
            af[mt] = *(const bf16x8*)&Alds[(wm + mt * 16 + lo) * TBK + quad * 8];
#pragma unroll
        for (int nt = 0; nt < NT; nt++)
            bfr[nt] = *(const bf16x8*)&Blds[(wn + nt * 16 + lo) * TBK + quad * 8];
#pragma unroll
        for (int mt = 0; mt < MT; mt++)
#pragma unroll
            for (int nt = 0; nt < NT; nt++)
                acc[mt][nt] = __builtin_amdgcn_mfma_f32_16x16x32_bf16(af[mt], bfr[nt], acc[mt][nt], 0, 0, 0);
    }

    // epilogue: D[row=quad*4+i][col=lo] per 16x16 tile
    if (EPI == 0) {
        u16* C = (u16*)Cp + (size_t)blockIdx.z * Msz * 512;
#pragma unroll
        for (int mt = 0; mt < MT; mt++) {
            int rb = m0 + wm + mt * 16 + quad * 4;
#pragma unroll
            for (int i = 0; i < 4; i++)
#pragma unroll
                for (int nt = 0; nt < NT; nt++)
                    C[(size_t)(rb + i) * 512 + n0 + wn + nt * 16 + lo] = f2b(acc[mt][nt][i]);
        }
    } else {
        u16* C = (u16*)Cp;
        float dv[NT];
#pragma unroll
        for (int nt = 0; nt < NT; nt++) dv[nt] = degv[n0 + wn + nt * 16 + lo];
#pragma unroll
        for (int mt = 0; mt < MT; mt++) {
            int rb = m0 + wm + mt * 16 + quad * 4;
#pragma unroll
            for (int i = 0; i < 4; i++)
#pragma unroll
                for (int nt = 0; nt < NT; nt++)
                    C[(size_t)(rb + i) * ldc + n0 + wn + nt * 16 + lo] =
                        f2b(acc[mt][nt][i] * dv[nt]);
        }
    }
}

// ---------------- launch ----------------

extern "C" void kernel_launch(void* const* d_in, const int* in_sizes, int n_in,
                              void* d_out, int out_size, void* d_ws, size_t ws_size,
                              hipStream_t stream) {
    const float* x    = (const float*)d_in[0];
    const float* H    = (const float*)d_in[1];
    const float* W    = (const float*)d_in[2];
    const float* V    = (const float*)d_in[3];
    const float* bias = (const float*)d_in[4];
    float* out  = (float*)d_out;                       // (N, FT)
    float* wout = out + (size_t)N_NODES * FT;          // (E,)
    (void)in_sizes; (void)n_in; (void)out_size; (void)ws_size;

    char* wsb = (char*)d_ws;
    float* wsf   = (float*)d_ws;
    float* xv    = wsf;               // 8192 f
    float* zsum  = wsf + 8192;        // 4096 f
    float* desum = wsf + 12288;       // 4096 f
    float* wde   = wsf + 16384;       // 4096 f
    float* degv  = wsf + 20480;       // 8192 f -> 114,688 B
    u8*    Hu8   = (u8*)(wsb + 114688);                  // 32 MB  -> 33,669,120
    u8*    HTu8  = (u8*)(wsb + 33669120);                // 32 MB  -> 67,223,552
    u16*   WT    = (u16*)(wsb + 67223552);               // 0.5 MB -> 67,747,840
    u16*   doutT = (u16*)(wsb + 67747840);               // 8 MB   -> 76,136,448
    u16*   t2T   = (u16*)(wsb + 76136448);               // 4 MB   -> 80,330,752
    u16*   P     = (u16*)(wsb + 80330752);               // 32 MB bf16 partials -> 113,885,184 (== proven)

    // scalar path
    zero_kernel<<<32, 256, 0, stream>>>(zsum, 8192);     // zsum+desum contiguous
    xv_kernel<<<N_NODES / 4, 256, 0, stream>>>(x, V, xv);
    cvt_colsum_kernel<<<dim3(4, 256), 256, 0, stream>>>(H, xv, Hu8, zsum, desum);
    sigmoid_kernel<<<N_EDGES / 256, 256, 0, stream>>>(zsum, desum, wout, wde);
    degv_kernel<<<N_NODES / 4, 256, 0, stream>>>(Hu8, wout, degv);
    wt_kernel<<<dim3(16, 16), dim3(32, 8), 0, stream>>>(W, WT);
    transH_kernel<<<dim3(N_EDGES / 64, N_NODES / 64), 256, 0, stream>>>(Hu8, HTu8);

    // G1: doutT[f,n] = degv[n] * sum_fi WT[f,fi]*x[n,fi]  (M=512, N=8192, K=512) 64x128 tile
    gemm5<2, 4, 0, 2, 1><<<dim3(FT / 64, N_NODES / 128, 1), 256, 0, stream>>>(
        WT, x, doutT, degv, FT, FT, FT, N_NODES, 0);

    // G2: P[z][e][f] = partial sum_n HTu8[e,n]*doutT[f,n]  (M=4096, N=512, K=8192, S=8) 128x256 tile
    gemm5<4, 8, 1, 0, 0><<<dim3(N_EDGES / 128, FT / 256, 8), 256, 0, stream>>>(
        HTu8, doutT, P, nullptr, N_NODES / 8, N_NODES, N_NODES, 512, N_EDGES);

    // t2T[f,e] = wde[e] * sum_s P
    t2t_kernel<<<dim3(FT / 32, N_EDGES / 32), dim3(32, 8), 0, stream>>>(P, wde, t2T);

    // G3: P[z][n][f] = partial sum_e Hu8[n,e]*t2T[f,e]   (M=8192, N=512, K=4096, S=4) 128x256 tile
    gemm5<4, 8, 1, 0, 0><<<dim3(N_NODES / 128, FT / 256, 4), 256, 0, stream>>>(
        Hu8, t2T, P, nullptr, N_EDGES / 4, N_EDGES, N_EDGES, 512, N_NODES);

    // out = degv ⊙ (sum_s P) + bias
    final_kernel<<<(N_NODES * FT / 8) / 256, 256, 0, stream>>>(P, degv, bias, out);
}